// Round 5
// baseline (50.245 us; speedup 1.0000x reference)
//
#include <hip/hip_runtime.h>
#include <math.h>

// MoE gate: logits = x @ W^T (T=131072, D=512, E=4), fp32 softmax,
// top-2 of (softmax + bias), gathered softmax weights + indices.
// Memory-bound (256 MiB x-read). R4 structure + ONE change: manual
// register double-buffer (prefetch next pair's loads before computing
// current pair) so every wave keeps loads in flight during the
// shuffle/epilogue chain.

constexpr int TOKENS = 131072;
constexpr int DIM = 512;

typedef float fvec4 __attribute__((ext_vector_type(4)));

__global__ __launch_bounds__(256) void gate_kernel(
    const float* __restrict__ x,      // [T, D]
    const float* __restrict__ w,      // [E, D]
    const float* __restrict__ bias,   // [E]
    float* __restrict__ out_w,        // [T, 2] fp32
    float* __restrict__ out_i)        // [T, 2] indices as float
{
    const int lane   = threadIdx.x & 63;
    const int wavesPerBlock = blockDim.x >> 6;
    const int wave   = blockIdx.x * wavesPerBlock + (threadIdx.x >> 6);
    const int nwaves = gridDim.x * wavesPerBlock;
    const int NPAIRS = TOKENS / 2;

    // Lane's slice: w[e][lane*8 .. lane*8+7]
    const float4 w0a = *reinterpret_cast<const float4*>(w + 0 * DIM + lane * 8);
    const float4 w0b = *reinterpret_cast<const float4*>(w + 0 * DIM + lane * 8 + 4);
    const float4 w1a = *reinterpret_cast<const float4*>(w + 1 * DIM + lane * 8);
    const float4 w1b = *reinterpret_cast<const float4*>(w + 1 * DIM + lane * 8 + 4);
    const float4 w2a = *reinterpret_cast<const float4*>(w + 2 * DIM + lane * 8);
    const float4 w2b = *reinterpret_cast<const float4*>(w + 2 * DIM + lane * 8 + 4);
    const float4 w3a = *reinterpret_cast<const float4*>(w + 3 * DIM + lane * 8);
    const float4 w3b = *reinterpret_cast<const float4*>(w + 3 * DIM + lane * 8 + 4);
    const float b0 = bias[0], b1 = bias[1], b2 = bias[2], b3 = bias[3];

    int tp = wave;
    if (tp >= NPAIRS) return;

    // initial load (pair tp)
    const float4* pA = reinterpret_cast<const float4*>(x + (size_t)(tp * 2) * DIM + lane * 8);
    const float4* pB = reinterpret_cast<const float4*>(x + (size_t)(tp * 2 + 1) * DIM + lane * 8);
    float4 xa0 = pA[0], xa1 = pA[1], xb0 = pB[0], xb1 = pB[1];

    while (true) {
        // ---- prefetch next pair BEFORE touching current data ----
        const int tn = tp + nwaves;
        const bool has_next = tn < NPAIRS;
        const int tpre = has_next ? tn : tp;   // dummy re-load keeps addresses in-bounds
        const float4* nA = reinterpret_cast<const float4*>(x + (size_t)(tpre * 2) * DIM + lane * 8);
        const float4* nB = reinterpret_cast<const float4*>(x + (size_t)(tpre * 2 + 1) * DIM + lane * 8);
        const float4 na0 = nA[0], na1 = nA[1], nb0 = nB[0], nb1 = nB[1];

        // ---- compute current pair ----
        const int tA = tp * 2;

        float A0 = xa0.x*w0a.x + xa0.y*w0a.y + xa0.z*w0a.z + xa0.w*w0a.w
                 + xa1.x*w0b.x + xa1.y*w0b.y + xa1.z*w0b.z + xa1.w*w0b.w;
        float A1 = xa0.x*w1a.x + xa0.y*w1a.y + xa0.z*w1a.z + xa0.w*w1a.w
                 + xa1.x*w1b.x + xa1.y*w1b.y + xa1.z*w1b.z + xa1.w*w1b.w;
        float A2 = xa0.x*w2a.x + xa0.y*w2a.y + xa0.z*w2a.z + xa0.w*w2a.w
                 + xa1.x*w2b.x + xa1.y*w2b.y + xa1.z*w2b.z + xa1.w*w2b.w;
        float A3 = xa0.x*w3a.x + xa0.y*w3a.y + xa0.z*w3a.z + xa0.w*w3a.w
                 + xa1.x*w3b.x + xa1.y*w3b.y + xa1.z*w3b.z + xa1.w*w3b.w;

        float B0 = xb0.x*w0a.x + xb0.y*w0a.y + xb0.z*w0a.z + xb0.w*w0a.w
                 + xb1.x*w0b.x + xb1.y*w0b.y + xb1.z*w0b.z + xb1.w*w0b.w;
        float B1 = xb0.x*w1a.x + xb0.y*w1a.y + xb0.z*w1a.z + xb0.w*w1a.w
                 + xb1.x*w1b.x + xb1.y*w1b.y + xb1.z*w1b.z + xb1.w*w1b.w;
        float B2 = xb0.x*w2a.x + xb0.y*w2a.y + xb0.z*w2a.z + xb0.w*w2a.w
                 + xb1.x*w2b.x + xb1.y*w2b.y + xb1.z*w2b.z + xb1.w*w2b.w;
        float B3 = xb0.x*w3a.x + xb0.y*w3a.y + xb0.z*w3a.z + xb0.w*w3a.w
                 + xb1.x*w3b.x + xb1.y*w3b.y + xb1.z*w3b.z + xb1.w*w3b.w;

        #pragma unroll
        for (int off = 1; off < 64; off <<= 1) {
            A0 += __shfl_xor(A0, off, 64);
            B0 += __shfl_xor(B0, off, 64);
            A1 += __shfl_xor(A1, off, 64);
            B1 += __shfl_xor(B1, off, 64);
            A2 += __shfl_xor(A2, off, 64);
            B2 += __shfl_xor(B2, off, 64);
            A3 += __shfl_xor(A3, off, 64);
            B3 += __shfl_xor(B3, off, 64);
        }

        float sA0, sA1, sA2, sA3;
        {
            const float m  = fmaxf(fmaxf(A0, A1), fmaxf(A2, A3));
            const float e0 = __expf(A0 - m), e1 = __expf(A1 - m);
            const float e2 = __expf(A2 - m), e3 = __expf(A3 - m);
            const float inv = 1.0f / (e0 + e1 + e2 + e3);
            sA0 = e0 * inv; sA1 = e1 * inv; sA2 = e2 * inv; sA3 = e3 * inv;
        }
        float sB0, sB1, sB2, sB3;
        {
            const float m  = fmaxf(fmaxf(B0, B1), fmaxf(B2, B3));
            const float e0 = __expf(B0 - m), e1 = __expf(B1 - m);
            const float e2 = __expf(B2 - m), e3 = __expf(B3 - m);
            const float inv = 1.0f / (e0 + e1 + e2 + e3);
            sB0 = e0 * inv; sB1 = e1 * inv; sB2 = e2 * inv; sB3 = e3 * inv;
        }

        const float pA0s = sA0 + b0, pA1s = sA1 + b1, pA2s = sA2 + b2, pA3s = sA3 + b3;
        int   iA0 = 0; float bvA = pA0s, svA0 = sA0;
        if (pA1s > bvA) { bvA = pA1s; svA0 = sA1; iA0 = 1; }
        if (pA2s > bvA) { bvA = pA2s; svA0 = sA2; iA0 = 2; }
        if (pA3s > bvA) { bvA = pA3s; svA0 = sA3; iA0 = 3; }
        int   iA1 = -1; float bvA1 = -INFINITY, svA1 = 0.0f;
        if (iA0 != 0 && pA0s > bvA1) { bvA1 = pA0s; svA1 = sA0; iA1 = 0; }
        if (iA0 != 1 && pA1s > bvA1) { bvA1 = pA1s; svA1 = sA1; iA1 = 1; }
        if (iA0 != 2 && pA2s > bvA1) { bvA1 = pA2s; svA1 = sA2; iA1 = 2; }
        if (iA0 != 3 && pA3s > bvA1) { bvA1 = pA3s; svA1 = sA3; iA1 = 3; }

        const float pB0s = sB0 + b0, pB1s = sB1 + b1, pB2s = sB2 + b2, pB3s = sB3 + b3;
        int   iB0 = 0; float bvB = pB0s, svB0 = sB0;
        if (pB1s > bvB) { bvB = pB1s; svB0 = sB1; iB0 = 1; }
        if (pB2s > bvB) { bvB = pB2s; svB0 = sB2; iB0 = 2; }
        if (pB3s > bvB) { bvB = pB3s; svB0 = sB3; iB0 = 3; }
        int   iB1 = -1; float bvB1 = -INFINITY, svB1 = 0.0f;
        if (iB0 != 0 && pB0s > bvB1) { bvB1 = pB0s; svB1 = sB0; iB1 = 0; }
        if (iB0 != 1 && pB1s > bvB1) { bvB1 = pB1s; svB1 = sB1; iB1 = 1; }
        if (iB0 != 2 && pB2s > bvB1) { bvB1 = pB2s; svB1 = sB2; iB1 = 2; }
        if (iB0 != 3 && pB3s > bvB1) { bvB1 = pB3s; svB1 = sB3; iB1 = 3; }

        if (lane == 0) {
            fvec4 wv; wv.x = svA0; wv.y = svA1; wv.z = svB0; wv.w = svB1;
            fvec4 iv; iv.x = (float)iA0; iv.y = (float)iA1; iv.z = (float)iB0; iv.w = (float)iB1;
            *reinterpret_cast<fvec4*>(out_w + 2 * (size_t)tA) = wv;
            *reinterpret_cast<fvec4*>(out_i + 2 * (size_t)tA) = iv;
        }

        if (!has_next) break;
        tp = tn;
        xa0 = na0; xa1 = na1; xb0 = nb0; xb1 = nb1;
    }
}

extern "C" void kernel_launch(void* const* d_in, const int* in_sizes, int n_in,
                              void* d_out, int out_size, void* d_ws, size_t ws_size,
                              hipStream_t stream) {
    const float* x    = (const float*)d_in[0];
    const float* w    = (const float*)d_in[1];
    const float* bias = (const float*)d_in[2];

    float* out_w = (float*)d_out;                      // [T,2] weights
    float* out_i = (float*)d_out + (size_t)TOKENS * 2; // [T,2] indices (as float)

    const int block  = 256;   // 4 waves/block
    const int blocks = 2048;  // 8192 waves -> 8 pair-iterations/wave
    gate_kernel<<<blocks, block, 0, stream>>>(x, w, bias, out_w, out_i);
}

// Round 7
// 45.601 us; speedup vs baseline: 1.1018x; 1.1018x over previous
//
#include <hip/hip_runtime.h>
#include <math.h>

// MoE gate: logits = x @ W^T (T=131072, D=512, E=4), fp32 softmax,
// top-2 of (softmax + bias), gathered softmax weights + indices.
// Memory-bound (256 MiB x-read). R4 structure + ONE change: DPP-based
// wave reduction (VALU pipe, zero LDS ops) instead of __shfl_xor
// butterfly (48 ds_bpermute/iter). Full sum lands in lane 63 -> lane 63
// is the store lane.

constexpr int TOKENS = 131072;
constexpr int DIM = 512;

typedef float fvec4 __attribute__((ext_vector_type(4)));

template <int CTRL>
__device__ __forceinline__ float dpp_add(float v) {
    // v_add_f32 with DPP-shifted operand; bound_ctrl=true shifts in 0.0f
    // at row edges (harmless for sums).
    const int r = __builtin_amdgcn_update_dpp(0, __float_as_int(v), CTRL, 0xf, 0xf, true);
    return v + __int_as_float(r);
}

// Wave64 sum; result valid in lane 63 only.
__device__ __forceinline__ float wave_sum63(float v) {
    v = dpp_add<0x111>(v);  // row_shr:1
    v = dpp_add<0x112>(v);  // row_shr:2
    v = dpp_add<0x114>(v);  // row_shr:4
    v = dpp_add<0x118>(v);  // row_shr:8  -> lane15 of each row = row sum
    v = dpp_add<0x142>(v);  // row_bcast:15
    v = dpp_add<0x143>(v);  // row_bcast:31 -> lane 63 = full sum
    return v;
}

__global__ __launch_bounds__(256) void gate_kernel(
    const float* __restrict__ x,      // [T, D]
    const float* __restrict__ w,      // [E, D]
    const float* __restrict__ bias,   // [E]
    float* __restrict__ out_w,        // [T, 2] fp32
    float* __restrict__ out_i)        // [T, 2] indices as float
{
    const int lane   = threadIdx.x & 63;
    const int wavesPerBlock = blockDim.x >> 6;
    const int wave   = blockIdx.x * wavesPerBlock + (threadIdx.x >> 6);
    const int nwaves = gridDim.x * wavesPerBlock;

    // Lane's slice: w[e][lane*8 .. lane*8+7]
    const float4 w0a = *reinterpret_cast<const float4*>(w + 0 * DIM + lane * 8);
    const float4 w0b = *reinterpret_cast<const float4*>(w + 0 * DIM + lane * 8 + 4);
    const float4 w1a = *reinterpret_cast<const float4*>(w + 1 * DIM + lane * 8);
    const float4 w1b = *reinterpret_cast<const float4*>(w + 1 * DIM + lane * 8 + 4);
    const float4 w2a = *reinterpret_cast<const float4*>(w + 2 * DIM + lane * 8);
    const float4 w2b = *reinterpret_cast<const float4*>(w + 2 * DIM + lane * 8 + 4);
    const float4 w3a = *reinterpret_cast<const float4*>(w + 3 * DIM + lane * 8);
    const float4 w3b = *reinterpret_cast<const float4*>(w + 3 * DIM + lane * 8 + 4);
    const float b0 = bias[0], b1 = bias[1], b2 = bias[2], b3 = bias[3];

    for (int tp = wave; tp < TOKENS / 2; tp += nwaves) {
        const int tA = tp * 2;
        const int tB = tA + 1;
        const float4* pA = reinterpret_cast<const float4*>(x + (size_t)tA * DIM + lane * 8);
        const float4* pB = reinterpret_cast<const float4*>(x + (size_t)tB * DIM + lane * 8);

        const float4 xa0 = pA[0];
        const float4 xa1 = pA[1];
        const float4 xb0 = pB[0];
        const float4 xb1 = pB[1];

        float A0 = xa0.x*w0a.x + xa0.y*w0a.y + xa0.z*w0a.z + xa0.w*w0a.w
                 + xa1.x*w0b.x + xa1.y*w0b.y + xa1.z*w0b.z + xa1.w*w0b.w;
        float A1 = xa0.x*w1a.x + xa0.y*w1a.y + xa0.z*w1a.z + xa0.w*w1a.w
                 + xa1.x*w1b.x + xa1.y*w1b.y + xa1.z*w1b.z + xa1.w*w1b.w;
        float A2 = xa0.x*w2a.x + xa0.y*w2a.y + xa0.z*w2a.z + xa0.w*w2a.w
                 + xa1.x*w2b.x + xa1.y*w2b.y + xa1.z*w2b.z + xa1.w*w2b.w;
        float A3 = xa0.x*w3a.x + xa0.y*w3a.y + xa0.z*w3a.z + xa0.w*w3a.w
                 + xa1.x*w3b.x + xa1.y*w3b.y + xa1.z*w3b.z + xa1.w*w3b.w;

        float B0 = xb0.x*w0a.x + xb0.y*w0a.y + xb0.z*w0a.z + xb0.w*w0a.w
                 + xb1.x*w0b.x + xb1.y*w0b.y + xb1.z*w0b.z + xb1.w*w0b.w;
        float B1 = xb0.x*w1a.x + xb0.y*w1a.y + xb0.z*w1a.z + xb0.w*w1a.w
                 + xb1.x*w1b.x + xb1.y*w1b.y + xb1.z*w1b.z + xb1.w*w1b.w;
        float B2 = xb0.x*w2a.x + xb0.y*w2a.y + xb0.z*w2a.z + xb0.w*w2a.w
                 + xb1.x*w2b.x + xb1.y*w2b.y + xb1.z*w2b.z + xb1.w*w2b.w;
        float B3 = xb0.x*w3a.x + xb0.y*w3a.y + xb0.z*w3a.z + xb0.w*w3a.w
                 + xb1.x*w3b.x + xb1.y*w3b.y + xb1.z*w3b.z + xb1.w*w3b.w;

        // DPP reductions (VALU pipe only); sums valid in lane 63.
        A0 = wave_sum63(A0);  B0 = wave_sum63(B0);
        A1 = wave_sum63(A1);  B1 = wave_sum63(B1);
        A2 = wave_sum63(A2);  B2 = wave_sum63(B2);
        A3 = wave_sum63(A3);  B3 = wave_sum63(B3);

        // --- softmax epilogues (values valid in lane 63; all lanes
        //     execute uniformly, lane 63 stores) ---
        float sA0, sA1, sA2, sA3;
        {
            const float m  = fmaxf(fmaxf(A0, A1), fmaxf(A2, A3));
            const float e0 = __expf(A0 - m), e1 = __expf(A1 - m);
            const float e2 = __expf(A2 - m), e3 = __expf(A3 - m);
            const float inv = 1.0f / (e0 + e1 + e2 + e3);
            sA0 = e0 * inv; sA1 = e1 * inv; sA2 = e2 * inv; sA3 = e3 * inv;
        }
        float sB0, sB1, sB2, sB3;
        {
            const float m  = fmaxf(fmaxf(B0, B1), fmaxf(B2, B3));
            const float e0 = __expf(B0 - m), e1 = __expf(B1 - m);
            const float e2 = __expf(B2 - m), e3 = __expf(B3 - m);
            const float inv = 1.0f / (e0 + e1 + e2 + e3);
            sB0 = e0 * inv; sB1 = e1 * inv; sB2 = e2 * inv; sB3 = e3 * inv;
        }

        // top-2 on biased scores (strict > keeps lowest index on ties)
        const float pA0s = sA0 + b0, pA1s = sA1 + b1, pA2s = sA2 + b2, pA3s = sA3 + b3;
        int   iA0 = 0; float bvA = pA0s, svA0 = sA0;
        if (pA1s > bvA) { bvA = pA1s; svA0 = sA1; iA0 = 1; }
        if (pA2s > bvA) { bvA = pA2s; svA0 = sA2; iA0 = 2; }
        if (pA3s > bvA) { bvA = pA3s; svA0 = sA3; iA0 = 3; }
        int   iA1 = -1; float bvA1 = -INFINITY, svA1 = 0.0f;
        if (iA0 != 0 && pA0s > bvA1) { bvA1 = pA0s; svA1 = sA0; iA1 = 0; }
        if (iA0 != 1 && pA1s > bvA1) { bvA1 = pA1s; svA1 = sA1; iA1 = 1; }
        if (iA0 != 2 && pA2s > bvA1) { bvA1 = pA2s; svA1 = sA2; iA1 = 2; }
        if (iA0 != 3 && pA3s > bvA1) { bvA1 = pA3s; svA1 = sA3; iA1 = 3; }

        const float pB0s = sB0 + b0, pB1s = sB1 + b1, pB2s = sB2 + b2, pB3s = sB3 + b3;
        int   iB0 = 0; float bvB = pB0s, svB0 = sB0;
        if (pB1s > bvB) { bvB = pB1s; svB0 = sB1; iB0 = 1; }
        if (pB2s > bvB) { bvB = pB2s; svB0 = sB2; iB0 = 2; }
        if (pB3s > bvB) { bvB = pB3s; svB0 = sB3; iB0 = 3; }
        int   iB1 = -1; float bvB1 = -INFINITY, svB1 = 0.0f;
        if (iB0 != 0 && pB0s > bvB1) { bvB1 = pB0s; svB1 = sB0; iB1 = 0; }
        if (iB0 != 1 && pB1s > bvB1) { bvB1 = pB1s; svB1 = sB1; iB1 = 1; }
        if (iB0 != 2 && pB2s > bvB1) { bvB1 = pB2s; svB1 = sB2; iB1 = 2; }
        if (iB0 != 3 && pB3s > bvB1) { bvB1 = pB3s; svB1 = sB3; iB1 = 3; }

        if (lane == 63) {
            fvec4 wv; wv.x = svA0; wv.y = svA1; wv.z = svB0; wv.w = svB1;
            fvec4 iv; iv.x = (float)iA0; iv.y = (float)iA1; iv.z = (float)iB0; iv.w = (float)iB1;
            *reinterpret_cast<fvec4*>(out_w + 2 * (size_t)tA) = wv;
            *reinterpret_cast<fvec4*>(out_i + 2 * (size_t)tA) = iv;
        }
    }
}

extern "C" void kernel_launch(void* const* d_in, const int* in_sizes, int n_in,
                              void* d_out, int out_size, void* d_ws, size_t ws_size,
                              hipStream_t stream) {
    const float* x    = (const float*)d_in[0];
    const float* w    = (const float*)d_in[1];
    const float* bias = (const float*)d_in[2];

    float* out_w = (float*)d_out;                      // [T,2] weights
    float* out_i = (float*)d_out + (size_t)TOKENS * 2; // [T,2] indices (as float)

    const int block  = 256;   // 4 waves/block
    const int blocks = 2048;  // 8192 waves -> 8 pair-iterations/wave
    gate_kernel<<<blocks, block, 0, stream>>>(x, w, bias, out_w, out_i);
}